// Round 7
// baseline (444.616 us; speedup 1.0000x reference)
//
#include <hip/hip_runtime.h>

typedef unsigned short ushort_t;
typedef unsigned int uint_t;
typedef __attribute__((ext_vector_type(8))) short short8;
typedef __attribute__((ext_vector_type(4))) float f32x4;
typedef __attribute__((ext_vector_type(4))) int i32x4;
typedef __attribute__((ext_vector_type(4))) uint_t u32x4;
typedef __attribute__((ext_vector_type(4))) ushort_t u16x4;

#define LRELU_SLOPE 0.2f
#define LOG2E 1.44269504f

// soft barrier: order LDS ops only; global loads stay IN FLIGHT across it.
#define SOFT_BARRIER() asm volatile("s_waitcnt lgkmcnt(0)\ns_barrier" ::: "memory")

// hardware packed f32->bf16 (RNE), 1 instr per pair (no builtin on gfx950)
static __device__ __forceinline__ uint_t cvt_pk_bf16(float lo, float hi) {
    uint_t r;
    asm("v_cvt_pk_bf16_f32 %0, %1, %2" : "=v"(r) : "v"(lo), "v"(hi));
    return r;
}
static __device__ __forceinline__ ushort_t f2bf_hw(float f) {
    return (ushort_t)(cvt_pk_bf16(f, f) & 0xffffu);
}
static __device__ __forceinline__ uint4 pack8(float4 a, float4 b) {
    uint4 r;
    r.x = cvt_pk_bf16(a.x, a.y);
    r.y = cvt_pk_bf16(a.z, a.w);
    r.z = cvt_pk_bf16(b.x, b.y);
    r.w = cvt_pk_bf16(b.z, b.w);
    return r;
}

// ---------------------------------------------------------------------------
// K1: wh = h @ W^T + Wb (bf16) + s_src/s_dst f32 partials (pre-scaled by
// log2e for K2's exp2). wh stored fragment-tiled whB[jt][kh][d][kq][8].
// Unchanged from round 6.
// ---------------------------------------------------------------------------
__launch_bounds__(256, 2)
__global__ void k1_gemm(const float* __restrict__ h, const float* __restrict__ W,
                        const float* __restrict__ Wb, const float* __restrict__ aw,
                        ushort_t* __restrict__ whB, float* __restrict__ s_src,
                        float* __restrict__ s_dst) {
    __shared__ __align__(16) ushort_t aT[256 * 72];  // W tile [o][k], stride 144 B
    __shared__ __align__(16) ushort_t bT[32 * 72];   // h tile [i][k]
    __shared__ float redLds[2][4][32];

    const int t = threadIdx.x;
    const int wv = t >> 6, ln = t & 63;
    const int i0 = blockIdx.x * 32;
    const int srow = t >> 3, sch = t & 7;
    const int row0 = ln & 15, kq = ln >> 4;

    f32x4 acc[4][2];
#pragma unroll
    for (int mt = 0; mt < 4; ++mt)
#pragma unroll
        for (int nt = 0; nt < 2; ++nt) acc[mt][nt] = (f32x4){0.f, 0.f, 0.f, 0.f};

    for (int k0 = 0; k0 < 512; k0 += 64) {
        __syncthreads();
#pragma unroll
        for (int r = 0; r < 8; ++r) {
            const float* gp = W + (size_t)(r * 32 + srow) * 512 + k0 + sch * 8;
            float4 x0 = *(const float4*)gp;
            float4 x1 = *(const float4*)(gp + 4);
            *(uint4*)(aT + (r * 32 + srow) * 72 + sch * 8) = pack8(x0, x1);
        }
        {
            const float* gp = h + (size_t)(i0 + srow) * 512 + k0 + sch * 8;
            float4 x0 = *(const float4*)gp;
            float4 x1 = *(const float4*)(gp + 4);
            *(uint4*)(bT + srow * 72 + sch * 8) = pack8(x0, x1);
        }
        __syncthreads();
#pragma unroll
        for (int ks = 0; ks < 2; ++ks) {
            short8 b[2];
#pragma unroll
            for (int nt = 0; nt < 2; ++nt)
                b[nt] = *(const short8*)(bT + (nt * 16 + row0) * 72 + ks * 32 + kq * 8);
#pragma unroll
            for (int mt = 0; mt < 4; ++mt) {
                short8 a = *(const short8*)(aT + (wv * 64 + mt * 16 + row0) * 72 + ks * 32 + kq * 8);
#pragma unroll
                for (int nt = 0; nt < 2; ++nt)
                    acc[mt][nt] = __builtin_amdgcn_mfma_f32_16x16x32_bf16(a, b[nt], acc[mt][nt], 0, 0, 0);
            }
        }
    }

    float psrc[2] = {0.f, 0.f}, pdst[2] = {0.f, 0.f};
#pragma unroll
    for (int mt = 0; mt < 4; ++mt) {
#pragma unroll
        for (int r = 0; r < 4; ++r) {
            const int o = wv * 64 + mt * 16 + (ln >> 4) * 4 + r;
            const float wbv = Wb[o];
            const float as = aw[o];
            const float ad = aw[256 + o];
#pragma unroll
            for (int nt = 0; nt < 2; ++nt) {
                const float v = acc[mt][nt][r] + wbv;
                psrc[nt] += v * as;
                pdst[nt] += v * ad;
                const int i = i0 + nt * 16 + (ln & 15);
                const int jt = i >> 6;
                const int khi = (i >> 5) & 1;
                const int kqi = (i >> 3) & 3;
                whB[((size_t)(jt * 2 + khi) * 256 + o) * 32 + kqi * 8 + (i & 7)] = f2bf_hw(v);
            }
        }
    }
#pragma unroll
    for (int off = 16; off < 64; off <<= 1) {
#pragma unroll
        for (int nt = 0; nt < 2; ++nt) {
            psrc[nt] += __shfl_xor(psrc[nt], off, 64);
            pdst[nt] += __shfl_xor(pdst[nt], off, 64);
        }
    }
    if (ln < 16) {
#pragma unroll
        for (int nt = 0; nt < 2; ++nt) {
            redLds[0][wv][nt * 16 + ln] = psrc[nt];
            redLds[1][wv][nt * 16 + ln] = pdst[nt];
        }
    }
    __syncthreads();
    if (t < 32) {
        float s = 0.f;
#pragma unroll
        for (int w = 0; w < 4; ++w) s += redLds[0][w][t];
        s_src[i0 + t] = s * LOG2E;  // pre-scaled for K2's exp2
    } else if (t < 64) {
        float s = 0.f;
#pragma unroll
        for (int w = 0; w < 4; ++w) s += redLds[1][w][t - 32];
        s_dst[i0 + t - 32] = s * LOG2E;  // pre-scaled for K2's exp2
    }
}

// ---------------------------------------------------------------------------
// K2: BM=64 i-tiles. NEW jsplit=4 -> grid 512 = 2 blocks/CU (4 waves/SIMD):
// the two co-resident blocks are not barrier-synced, so one block's
// compute/issue covers the other's vmcnt stall (TLP for the burst-stall
// pattern; 1 block/CU left ~1200 cy/iter of all-wave stall uncovered).
// LDS 66.8KB x2 = 133.6KB < 160KB; VGPR 84 < 128 cap. Soft barrier kept.
// ---------------------------------------------------------------------------
__launch_bounds__(512, 4)
__global__ void k2_attn(const int* __restrict__ adj, const ushort_t* __restrict__ whB,
                        const float* __restrict__ s_src, const float* __restrict__ s_dst,
                        const float* __restrict__ ab_p, float* __restrict__ out,
                        float* __restrict__ part, float* __restrict__ zp,
                        int jsplit, int jslog) {
    // exch: 256 lanes * 65 f32 stride = 66560 B, unioned with pbuf
    // (2*64*72 ushort = 18432 B, double-buffered p tile). zLds after.
    __shared__ __align__(16) char smem[66560 + 256];
    ushort_t* pbuf = (ushort_t*)smem;
    float* exch = (float*)smem;
    float* zLds = (float*)(smem + 66560);

    const int t = threadIdx.x;
    const int wv = t >> 6, ln = t & 63;
    const int dq = wv & 3, kh = wv >> 2;
    const int row0 = ln & 15, kq = ln >> 4;
    const int jb = (int)blockIdx.x & (jsplit - 1);
    const int ib = (int)blockIdx.x >> jslog;
    const int i0 = ib * 64;
    const int jlen = 8192 >> jslog;
    const int jbase = jb * jlen;
    const int iters = jlen >> 6;
    const int prow = t >> 4, pjc = t & 15;  // p-compute: rows prow & prow+32, 4 j's

    const float ab = ab_p[0] * LOG2E;
    const float ssa0 = s_src[i0 + prow] + ab;        // hoisted ssrc+ab (log2e-scaled)
    const float ssa1 = s_src[i0 + 32 + prow] + ab;

    const int* aBase0 = adj + (size_t)(i0 + prow) * 8192 + jbase + pjc * 4;
    const int* aBase1 = aBase0 + (size_t)32 * 8192;
    const float* sBase = s_dst + jbase + pjc * 4;
    // per-lane B-fragment pointer: contiguous 1 KB per (jt,kh,dq,nt) wave read
    const ushort_t* bBase = whB + ((size_t)(jbase >> 6) * 2 + kh) * 8192
                            + (dq * 64 + row0) * 32 + kq * 8;

    f32x4 acc[4][4];  // [mt][nt]
#pragma unroll
    for (int mt = 0; mt < 4; ++mt)
#pragma unroll
        for (int nt = 0; nt < 4; ++nt) acc[mt][nt] = (f32x4){0.f, 0.f, 0.f, 0.f};
    float zacc0 = 0.f, zacc1 = 0.f;

    // prefetch tile 0 (depth-1)
    i32x4 Av0 = __builtin_nontemporal_load((const i32x4*)aBase0);
    i32x4 Av1 = __builtin_nontemporal_load((const i32x4*)aBase1);
    f32x4 Sv = *(const f32x4*)sBase;
    short8 Bv[4];
#pragma unroll
    for (int nt = 0; nt < 4; ++nt) Bv[nt] = *(const short8*)(bBase + nt * 512);

#pragma unroll 2
    for (int it = 0; it < iters; ++it) {
        const int itn = (it < iters - 1) ? it + 1 : it;
        i32x4 Ac0 = Av0, Ac1 = Av1;
        f32x4 Sc = Sv;
        short8 Bc[4];
#pragma unroll
        for (int nt = 0; nt < 4; ++nt) Bc[nt] = Bv[nt];
        // issue next-tile loads (stay in flight across the soft barrier)
        Av0 = __builtin_nontemporal_load((const i32x4*)(aBase0 + itn * 64));
        Av1 = __builtin_nontemporal_load((const i32x4*)(aBase1 + itn * 64));
        Sv = *(const f32x4*)(sBase + itn * 64);
        {
            const ushort_t* bN = bBase + (size_t)itn * 16384;
#pragma unroll
            for (int nt = 0; nt < 4; ++nt) Bv[nt] = *(const short8*)(bN + nt * 512);
        }

        // p tile (both rows) for this iteration -> pbuf[it&1]
        {
            ushort_t* pc = pbuf + (it & 1) * 4608;
            float p[4];
            float z4 = 0.f;
#pragma unroll
            for (int k = 0; k < 4; ++k) {
                float sc = ssa0 + Sc[k];
                sc = fmaxf(sc, LRELU_SLOPE * sc);   // lrelu (log2e-scaled domain)
                sc = fminf(sc, 86.562f);            // 60 * log2e
                float pv = (Ac0[k] > 0) ? __builtin_amdgcn_exp2f(sc) : 0.f;
                z4 += pv;
                p[k] = pv;
            }
            zacc0 += z4;
            uint2 w0;
            w0.x = cvt_pk_bf16(p[0], p[1]);
            w0.y = cvt_pk_bf16(p[2], p[3]);
            *(uint2*)(pc + prow * 72 + pjc * 4) = w0;
            z4 = 0.f;
#pragma unroll
            for (int k = 0; k < 4; ++k) {
                float sc = ssa1 + Sc[k];
                sc = fmaxf(sc, LRELU_SLOPE * sc);
                sc = fminf(sc, 86.562f);
                float pv = (Ac1[k] > 0) ? __builtin_amdgcn_exp2f(sc) : 0.f;
                z4 += pv;
                p[k] = pv;
            }
            zacc1 += z4;
            uint2 w1;
            w1.x = cvt_pk_bf16(p[0], p[1]);
            w1.y = cvt_pk_bf16(p[2], p[3]);
            *(uint2*)(pc + (32 + prow) * 72 + pjc * 4) = w1;
        }
        SOFT_BARRIER();  // p visible (lgkm drained); global prefetches stay in flight
        {
            const ushort_t* pc = pbuf + (it & 1) * 4608;
#pragma unroll
            for (int mt = 0; mt < 4; ++mt) {
                short8 a = *(const short8*)(pc + (mt * 16 + row0) * 72 + kh * 32 + kq * 8);
#pragma unroll
                for (int nt = 0; nt < 4; ++nt)
                    acc[mt][nt] = __builtin_amdgcn_mfma_f32_16x16x32_bf16(a, Bc[nt], acc[mt][nt], 0, 0, 0);
            }
        }
    }

    // per-row Z from the 16 consecutive lanes of each prow group
    zacc0 += __shfl_xor(zacc0, 1, 64);
    zacc1 += __shfl_xor(zacc1, 1, 64);
    zacc0 += __shfl_xor(zacc0, 2, 64);
    zacc1 += __shfl_xor(zacc1, 2, 64);
    zacc0 += __shfl_xor(zacc0, 4, 64);
    zacc1 += __shfl_xor(zacc1, 4, 64);
    zacc0 += __shfl_xor(zacc0, 8, 64);
    zacc1 += __shfl_xor(zacc1, 8, 64);
    if ((t & 15) == 0) {
        if (jsplit > 1) {
            zp[(size_t)jb * 8192 + i0 + prow] = zacc0;
            zp[(size_t)jb * 8192 + i0 + 32 + prow] = zacc1;
        } else {
            zLds[prow] = 1.0f / fmaxf(zacc0, 1e-30f);
            zLds[32 + prow] = 1.0f / fmaxf(zacc1, 1e-30f);
        }
    }

    __syncthreads();  // full barrier: all MFMA LDS reads done; pbuf -> exch reuse
    if (kh == 1) {
        float* p = exch + (dq * 64 + ln) * 65;  // stride-65: conflict-free
#pragma unroll
        for (int mt = 0; mt < 4; ++mt)
#pragma unroll
            for (int nt = 0; nt < 4; ++nt)
#pragma unroll
                for (int r = 0; r < 4; ++r) p[mt * 16 + nt * 4 + r] = acc[mt][nt][r];
    }
    __syncthreads();
    if (kh == 0) {
        float* outp = (jb == 0) ? out : part + (size_t)(jb - 1) * 2097152;
        const float* p = exch + (dq * 64 + ln) * 65;
#pragma unroll
        for (int mt = 0; mt < 4; ++mt)
#pragma unroll
            for (int nt = 0; nt < 4; ++nt)
#pragma unroll
                for (int r = 0; r < 4; ++r) {
                    const int il = mt * 16 + (ln >> 4) * 4 + r;
                    const int d = dq * 64 + nt * 16 + (ln & 15);
                    const float v = acc[mt][nt][r] + p[mt * 16 + nt * 4 + r];
                    if (jsplit > 1)
                        outp[(size_t)(i0 + il) * 256 + d] = v;
                    else
                        outp[(size_t)(i0 + il) * 256 + d] = v * zLds[il];
                }
    }
}

// ---------------------------------------------------------------------------
// K3 (jsplit==4): out = (out + p1 + p2 + p3) / (z0+z1+z2+z3). grid 8192x256.
// ---------------------------------------------------------------------------
__global__ void k3_norm(float* __restrict__ out, const float* __restrict__ part,
                        const float* __restrict__ zp) {
    const int i = blockIdx.x, t = threadIdx.x;
    const float z = zp[i] + zp[8192 + i] + zp[16384 + i] + zp[24576 + i];
    const float rz = 1.0f / fmaxf(z, 1e-30f);
    const size_t idx = (size_t)i * 256 + t;
    const float v = out[idx] + part[idx] + part[2097152 + idx] + part[4194304 + idx];
    out[idx] = v * rz;
}

extern "C" void kernel_launch(void* const* d_in, const int* in_sizes, int n_in, void* d_out,
                              int out_size, void* d_ws, size_t ws_size, hipStream_t stream) {
    // identify inputs by flat size (validated r7/r8)
    int order[16];
    for (int i = 0; i < n_in; ++i) order[i] = i;
    for (int a = 0; a < n_in; ++a)
        for (int b = a + 1; b < n_in; ++b)
            if (in_sizes[order[b]] < in_sizes[order[a]]) {
                int tmp = order[a]; order[a] = order[b]; order[b] = tmp;
            }
    const float* ab = (const float*)d_in[order[0]];
    const float* Wb = (const float*)d_in[order[1]];
    const float* aw = (const float*)d_in[order[2]];
    const float* Ww = (const float*)d_in[order[3]];
    const float* h = (const float*)d_in[order[4]];
    const int* adj = (const int*)d_in[order[5]];

    char* ws = (char*)d_ws;
    ushort_t* whB = (ushort_t*)ws;                 // 4 MB (fragment-tiled wh)
    float* ssrc = (float*)(ws + 4194304);          // 32 KB
    float* sdst = (float*)(ws + 4227072);          // 32 KB
    float* part = (float*)(ws + 4259840);          // 3 x 8 MB (jb=1..3 partials)
    float* zp = (float*)(ws + 29425664);           // 128 KB (4 x 8192 f32)
    const size_t need = 29556736;
    const int jsplit = (ws_size >= need) ? 4 : 1;
    const int jslog = (jsplit == 4) ? 2 : 0;

    hipLaunchKernelGGL(k1_gemm, dim3(256), dim3(256), 0, stream, h, Ww, Wb, aw, whB, ssrc, sdst);
    hipLaunchKernelGGL(k2_attn, dim3(128 * jsplit), dim3(512), 0, stream, adj, whB, ssrc, sdst,
                       ab, (float*)d_out, part, zp, jsplit, jslog);
    if (jsplit == 4)
        hipLaunchKernelGGL(k3_norm, dim3(8192), dim3(256), 0, stream, (float*)d_out, part, zp);
}

// Round 8
// 418.295 us; speedup vs baseline: 1.0629x; 1.0629x over previous
//
#include <hip/hip_runtime.h>

typedef unsigned short ushort_t;
typedef unsigned int uint_t;
typedef __attribute__((ext_vector_type(8))) short short8;
typedef __attribute__((ext_vector_type(4))) float f32x4;
typedef __attribute__((ext_vector_type(4))) int i32x4;
typedef __attribute__((ext_vector_type(4))) uint_t u32x4;
typedef __attribute__((ext_vector_type(4))) ushort_t u16x4;

#define LRELU_SLOPE 0.2f
#define LOG2E 1.44269504f

// soft barrier: order LDS ops only; global loads stay IN FLIGHT across it.
#define SOFT_BARRIER() asm volatile("s_waitcnt lgkmcnt(0)\ns_barrier" ::: "memory")

// hardware packed f32->bf16 (RNE), 1 instr per pair (no builtin on gfx950)
static __device__ __forceinline__ uint_t cvt_pk_bf16(float lo, float hi) {
    uint_t r;
    asm("v_cvt_pk_bf16_f32 %0, %1, %2" : "=v"(r) : "v"(lo), "v"(hi));
    return r;
}
static __device__ __forceinline__ ushort_t f2bf_hw(float f) {
    return (ushort_t)(cvt_pk_bf16(f, f) & 0xffffu);
}
static __device__ __forceinline__ uint4 pack8(float4 a, float4 b) {
    uint4 r;
    r.x = cvt_pk_bf16(a.x, a.y);
    r.y = cvt_pk_bf16(a.z, a.w);
    r.z = cvt_pk_bf16(b.x, b.y);
    r.w = cvt_pk_bf16(b.z, b.w);
    return r;
}

// ---------------------------------------------------------------------------
// K1: wh = h @ W^T + Wb (bf16) + s_src/s_dst f32 partials (pre-scaled by
// log2e for K2's exp2). wh stored fragment-tiled whB[jt][kh][d][kq][8].
// Unchanged (r6-measured).
// ---------------------------------------------------------------------------
__launch_bounds__(256, 2)
__global__ void k1_gemm(const float* __restrict__ h, const float* __restrict__ W,
                        const float* __restrict__ Wb, const float* __restrict__ aw,
                        ushort_t* __restrict__ whB, float* __restrict__ s_src,
                        float* __restrict__ s_dst) {
    __shared__ __align__(16) ushort_t aT[256 * 72];  // W tile [o][k], stride 144 B
    __shared__ __align__(16) ushort_t bT[32 * 72];   // h tile [i][k]
    __shared__ float redLds[2][4][32];

    const int t = threadIdx.x;
    const int wv = t >> 6, ln = t & 63;
    const int i0 = blockIdx.x * 32;
    const int srow = t >> 3, sch = t & 7;
    const int row0 = ln & 15, kq = ln >> 4;

    f32x4 acc[4][2];
#pragma unroll
    for (int mt = 0; mt < 4; ++mt)
#pragma unroll
        for (int nt = 0; nt < 2; ++nt) acc[mt][nt] = (f32x4){0.f, 0.f, 0.f, 0.f};

    for (int k0 = 0; k0 < 512; k0 += 64) {
        __syncthreads();
#pragma unroll
        for (int r = 0; r < 8; ++r) {
            const float* gp = W + (size_t)(r * 32 + srow) * 512 + k0 + sch * 8;
            float4 x0 = *(const float4*)gp;
            float4 x1 = *(const float4*)(gp + 4);
            *(uint4*)(aT + (r * 32 + srow) * 72 + sch * 8) = pack8(x0, x1);
        }
        {
            const float* gp = h + (size_t)(i0 + srow) * 512 + k0 + sch * 8;
            float4 x0 = *(const float4*)gp;
            float4 x1 = *(const float4*)(gp + 4);
            *(uint4*)(bT + srow * 72 + sch * 8) = pack8(x0, x1);
        }
        __syncthreads();
#pragma unroll
        for (int ks = 0; ks < 2; ++ks) {
            short8 b[2];
#pragma unroll
            for (int nt = 0; nt < 2; ++nt)
                b[nt] = *(const short8*)(bT + (nt * 16 + row0) * 72 + ks * 32 + kq * 8);
#pragma unroll
            for (int mt = 0; mt < 4; ++mt) {
                short8 a = *(const short8*)(aT + (wv * 64 + mt * 16 + row0) * 72 + ks * 32 + kq * 8);
#pragma unroll
                for (int nt = 0; nt < 2; ++nt)
                    acc[mt][nt] = __builtin_amdgcn_mfma_f32_16x16x32_bf16(a, b[nt], acc[mt][nt], 0, 0, 0);
            }
        }
    }

    float psrc[2] = {0.f, 0.f}, pdst[2] = {0.f, 0.f};
#pragma unroll
    for (int mt = 0; mt < 4; ++mt) {
#pragma unroll
        for (int r = 0; r < 4; ++r) {
            const int o = wv * 64 + mt * 16 + (ln >> 4) * 4 + r;
            const float wbv = Wb[o];
            const float as = aw[o];
            const float ad = aw[256 + o];
#pragma unroll
            for (int nt = 0; nt < 2; ++nt) {
                const float v = acc[mt][nt][r] + wbv;
                psrc[nt] += v * as;
                pdst[nt] += v * ad;
                const int i = i0 + nt * 16 + (ln & 15);
                const int jt = i >> 6;
                const int khi = (i >> 5) & 1;
                const int kqi = (i >> 3) & 3;
                whB[((size_t)(jt * 2 + khi) * 256 + o) * 32 + kqi * 8 + (i & 7)] = f2bf_hw(v);
            }
        }
    }
#pragma unroll
    for (int off = 16; off < 64; off <<= 1) {
#pragma unroll
        for (int nt = 0; nt < 2; ++nt) {
            psrc[nt] += __shfl_xor(psrc[nt], off, 64);
            pdst[nt] += __shfl_xor(pdst[nt], off, 64);
        }
    }
    if (ln < 16) {
#pragma unroll
        for (int nt = 0; nt < 2; ++nt) {
            redLds[0][wv][nt * 16 + ln] = psrc[nt];
            redLds[1][wv][nt * 16 + ln] = pdst[nt];
        }
    }
    __syncthreads();
    if (t < 32) {
        float s = 0.f;
#pragma unroll
        for (int w = 0; w < 4; ++w) s += redLds[0][w][t];
        s_src[i0 + t] = s * LOG2E;  // pre-scaled for K2's exp2
    } else if (t < 64) {
        float s = 0.f;
#pragma unroll
        for (int w = 0; w < 4; ++w) s += redLds[1][w][t - 32];
        s_dst[i0 + t - 32] = s * LOG2E;  // pre-scaled for K2's exp2
    }
}

// ---------------------------------------------------------------------------
// K2: BM=64, jsplit=2 (grid 256 = 1 block/CU, 8 waves) — r6 structure.
// NEW: uniform DEPTH-2 register rotation for all 7 per-iter loads. With the
// soft barrier (no vmcnt drain), each batch now has two full iterations in
// flight before its consume-wait; the compiler emits counted vmcnt (one
// batch outstanding allowed). r3's depth-2 null was measured under the
// vmcnt-draining __syncthreads and does not apply to this regime.
// Slots indexed (it&1) under unroll-2 -> compile-time (no scratch).
// ---------------------------------------------------------------------------
__launch_bounds__(512, 2)
__global__ void k2_attn(const int* __restrict__ adj, const ushort_t* __restrict__ whB,
                        const float* __restrict__ s_src, const float* __restrict__ s_dst,
                        const float* __restrict__ ab_p, float* __restrict__ out0,
                        float* __restrict__ out1, float* __restrict__ zp, int jsplit) {
    // exch: 256 lanes * 65 f32 stride = 66560 B, unioned with pbuf
    // (2*64*72 ushort = 18432 B, double-buffered p tile). zLds after.
    __shared__ __align__(16) char smem[66560 + 256];
    ushort_t* pbuf = (ushort_t*)smem;
    float* exch = (float*)smem;
    float* zLds = (float*)(smem + 66560);

    const int t = threadIdx.x;
    const int wv = t >> 6, ln = t & 63;
    const int dq = wv & 3, kh = wv >> 2;
    const int row0 = ln & 15, kq = ln >> 4;
    const int split2 = (jsplit == 2);
    const int jb = split2 ? (int)(blockIdx.x & 1) : 0;
    const int ib = split2 ? (int)(blockIdx.x >> 1) : (int)blockIdx.x;
    const int i0 = ib * 64;
    const int jlen = split2 ? 4096 : 8192;
    const int jbase = jb * jlen;
    const int iters = jlen >> 6;
    const int prow = t >> 4, pjc = t & 15;  // p-compute: rows prow & prow+32, 4 j's

    const float ab = ab_p[0] * LOG2E;
    const float ssa0 = s_src[i0 + prow] + ab;        // hoisted ssrc+ab (log2e-scaled)
    const float ssa1 = s_src[i0 + 32 + prow] + ab;

    const int* aBase0 = adj + (size_t)(i0 + prow) * 8192 + jbase + pjc * 4;
    const int* aBase1 = aBase0 + (size_t)32 * 8192;
    const float* sBase = s_dst + jbase + pjc * 4;
    // per-lane B-fragment pointer: contiguous 1 KB per (jt,kh,dq,nt) wave read
    const ushort_t* bBase = whB + ((size_t)(jbase >> 6) * 2 + kh) * 8192
                            + (dq * 64 + row0) * 32 + kq * 8;

    f32x4 acc[4][4];  // [mt][nt]
#pragma unroll
    for (int mt = 0; mt < 4; ++mt)
#pragma unroll
        for (int nt = 0; nt < 4; ++nt) acc[mt][nt] = (f32x4){0.f, 0.f, 0.f, 0.f};
    float zacc0 = 0.f, zacc1 = 0.f;

    // depth-2 prefetch: slot sl holds tile (it) with it&1==sl; 2 batches in flight
    i32x4 A0[2], A1[2];
    f32x4 S[2];
    short8 B[2][4];
    {
        const int t1 = (iters > 1) ? 1 : 0;
        A0[0] = __builtin_nontemporal_load((const i32x4*)aBase0);
        A1[0] = __builtin_nontemporal_load((const i32x4*)aBase1);
        S[0] = *(const f32x4*)sBase;
#pragma unroll
        for (int nt = 0; nt < 4; ++nt) B[0][nt] = *(const short8*)(bBase + nt * 512);
        A0[1] = __builtin_nontemporal_load((const i32x4*)(aBase0 + t1 * 64));
        A1[1] = __builtin_nontemporal_load((const i32x4*)(aBase1 + t1 * 64));
        S[1] = *(const f32x4*)(sBase + t1 * 64);
        const ushort_t* b1 = bBase + (size_t)t1 * 16384;
#pragma unroll
        for (int nt = 0; nt < 4; ++nt) B[1][nt] = *(const short8*)(b1 + nt * 512);
    }

#pragma unroll 2
    for (int it = 0; it < iters; ++it) {
        const int sl = it & 1;
        const int itp = (it + 2 < iters) ? (it + 2) : (iters - 1);
        // consume batch it (issued 2 iterations ago)
        i32x4 Ac0 = A0[sl], Ac1 = A1[sl];
        f32x4 Sc = S[sl];
        short8 Bc[4];
#pragma unroll
        for (int nt = 0; nt < 4; ++nt) Bc[nt] = B[sl][nt];
        // refill slot with tile it+2 (stays in flight across 2 soft barriers)
        A0[sl] = __builtin_nontemporal_load((const i32x4*)(aBase0 + itp * 64));
        A1[sl] = __builtin_nontemporal_load((const i32x4*)(aBase1 + itp * 64));
        S[sl] = *(const f32x4*)(sBase + itp * 64);
        {
            const ushort_t* bN = bBase + (size_t)itp * 16384;
#pragma unroll
            for (int nt = 0; nt < 4; ++nt) B[sl][nt] = *(const short8*)(bN + nt * 512);
        }

        // p tile (both rows) for this iteration -> pbuf[sl]
        {
            ushort_t* pc = pbuf + sl * 4608;
            float p[4];
            float z4 = 0.f;
#pragma unroll
            for (int k = 0; k < 4; ++k) {
                float sc = ssa0 + Sc[k];
                sc = fmaxf(sc, LRELU_SLOPE * sc);   // lrelu (log2e-scaled domain)
                sc = fminf(sc, 86.562f);            // 60 * log2e
                float pv = (Ac0[k] > 0) ? __builtin_amdgcn_exp2f(sc) : 0.f;
                z4 += pv;
                p[k] = pv;
            }
            zacc0 += z4;
            uint2 w0;
            w0.x = cvt_pk_bf16(p[0], p[1]);
            w0.y = cvt_pk_bf16(p[2], p[3]);
            *(uint2*)(pc + prow * 72 + pjc * 4) = w0;
            z4 = 0.f;
#pragma unroll
            for (int k = 0; k < 4; ++k) {
                float sc = ssa1 + Sc[k];
                sc = fmaxf(sc, LRELU_SLOPE * sc);
                sc = fminf(sc, 86.562f);
                float pv = (Ac1[k] > 0) ? __builtin_amdgcn_exp2f(sc) : 0.f;
                z4 += pv;
                p[k] = pv;
            }
            zacc1 += z4;
            uint2 w1;
            w1.x = cvt_pk_bf16(p[0], p[1]);
            w1.y = cvt_pk_bf16(p[2], p[3]);
            *(uint2*)(pc + (32 + prow) * 72 + pjc * 4) = w1;
        }
        SOFT_BARRIER();  // p visible (lgkm drained); global prefetches stay in flight
        {
            const ushort_t* pc = pbuf + sl * 4608;
#pragma unroll
            for (int mt = 0; mt < 4; ++mt) {
                short8 a = *(const short8*)(pc + (mt * 16 + row0) * 72 + kh * 32 + kq * 8);
#pragma unroll
                for (int nt = 0; nt < 4; ++nt)
                    acc[mt][nt] = __builtin_amdgcn_mfma_f32_16x16x32_bf16(a, Bc[nt], acc[mt][nt], 0, 0, 0);
            }
        }
    }

    // per-row Z from the 16 consecutive lanes of each prow group
    zacc0 += __shfl_xor(zacc0, 1, 64);
    zacc1 += __shfl_xor(zacc1, 1, 64);
    zacc0 += __shfl_xor(zacc0, 2, 64);
    zacc1 += __shfl_xor(zacc1, 2, 64);
    zacc0 += __shfl_xor(zacc0, 4, 64);
    zacc1 += __shfl_xor(zacc1, 4, 64);
    zacc0 += __shfl_xor(zacc0, 8, 64);
    zacc1 += __shfl_xor(zacc1, 8, 64);
    if ((t & 15) == 0) {
        if (split2) {
            zp[(size_t)jb * 8192 + i0 + prow] = zacc0;
            zp[(size_t)jb * 8192 + i0 + 32 + prow] = zacc1;
        } else {
            zLds[prow] = 1.0f / fmaxf(zacc0, 1e-30f);
            zLds[32 + prow] = 1.0f / fmaxf(zacc1, 1e-30f);
        }
    }

    __syncthreads();  // full barrier: all MFMA LDS reads done; pbuf -> exch reuse
    if (kh == 1) {
        float* p = exch + (dq * 64 + ln) * 65;  // stride-65: conflict-free
#pragma unroll
        for (int mt = 0; mt < 4; ++mt)
#pragma unroll
            for (int nt = 0; nt < 4; ++nt)
#pragma unroll
                for (int r = 0; r < 4; ++r) p[mt * 16 + nt * 4 + r] = acc[mt][nt][r];
    }
    __syncthreads();
    if (kh == 0) {
        float* outp = (jb == 0) ? out0 : out1;
        const float* p = exch + (dq * 64 + ln) * 65;
#pragma unroll
        for (int mt = 0; mt < 4; ++mt)
#pragma unroll
            for (int nt = 0; nt < 4; ++nt)
#pragma unroll
                for (int r = 0; r < 4; ++r) {
                    const int il = mt * 16 + (ln >> 4) * 4 + r;
                    const int d = dq * 64 + nt * 16 + (ln & 15);
                    const float v = acc[mt][nt][r] + p[mt * 16 + nt * 4 + r];
                    if (split2)
                        outp[(size_t)(i0 + il) * 256 + d] = v;
                    else
                        outp[(size_t)(i0 + il) * 256 + d] = v * zLds[il];
                }
    }
}

// ---------------------------------------------------------------------------
// K3 (jsplit==2 only): out = (out + part) / (z0 + z1). grid 8192 x 256.
// ---------------------------------------------------------------------------
__global__ void k3_norm(float* __restrict__ out, const float* __restrict__ part,
                        const float* __restrict__ zp) {
    const int i = blockIdx.x, t = threadIdx.x;
    const float rz = 1.0f / fmaxf(zp[i] + zp[8192 + i], 1e-30f);
    const size_t idx = (size_t)i * 256 + t;
    out[idx] = (out[idx] + part[idx]) * rz;
}

extern "C" void kernel_launch(void* const* d_in, const int* in_sizes, int n_in, void* d_out,
                              int out_size, void* d_ws, size_t ws_size, hipStream_t stream) {
    // identify inputs by flat size (validated r7/r8)
    int order[16];
    for (int i = 0; i < n_in; ++i) order[i] = i;
    for (int a = 0; a < n_in; ++a)
        for (int b = a + 1; b < n_in; ++b)
            if (in_sizes[order[b]] < in_sizes[order[a]]) {
                int tmp = order[a]; order[a] = order[b]; order[b] = tmp;
            }
    const float* ab = (const float*)d_in[order[0]];
    const float* Wb = (const float*)d_in[order[1]];
    const float* aw = (const float*)d_in[order[2]];
    const float* Ww = (const float*)d_in[order[3]];
    const float* h = (const float*)d_in[order[4]];
    const int* adj = (const int*)d_in[order[5]];

    char* ws = (char*)d_ws;
    ushort_t* whB = (ushort_t*)ws;                 // 4 MB (fragment-tiled wh)
    float* ssrc = (float*)(ws + 4194304);          // 32 KB
    float* sdst = (float*)(ws + 4227072);          // 32 KB
    float* part = (float*)(ws + 4259840);          // 8 MB (jb=1 partial)
    float* zp = (float*)(ws + 12648448);           // 64 KB (2 x 8192 f32)
    const size_t need = 12713984;
    const int jsplit = (ws_size >= need) ? 2 : 1;

    hipLaunchKernelGGL(k1_gemm, dim3(256), dim3(256), 0, stream, h, Ww, Wb, aw, whB, ssrc, sdst);
    hipLaunchKernelGGL(k2_attn, dim3(128 * jsplit), dim3(512), 0, stream, adj, whB, ssrc, sdst,
                       ab, (float*)d_out, part, zp, jsplit);
    if (jsplit == 2)
        hipLaunchKernelGGL(k3_norm, dim3(8192), dim3(256), 0, stream, (float*)d_out, part, zp);
}

// Round 9
// 415.142 us; speedup vs baseline: 1.0710x; 1.0076x over previous
//
#include <hip/hip_runtime.h>

typedef unsigned short ushort_t;
typedef unsigned int uint_t;
typedef __attribute__((ext_vector_type(8))) short short8;
typedef __attribute__((ext_vector_type(4))) float f32x4;
typedef __attribute__((ext_vector_type(4))) int i32x4;
typedef __attribute__((ext_vector_type(4))) uint_t u32x4;
typedef __attribute__((ext_vector_type(4))) ushort_t u16x4;

#define LRELU_SLOPE 0.2f
#define LOG2E 1.44269504f

// soft barrier: order LDS ops only; global loads stay IN FLIGHT across it.
// (__syncthreads drains vmcnt(0) -> every barrier re-exposes full HBM latency
// of the just-issued prefetch loads; this is the m97 barrier-drain pathology.)
#define SOFT_BARRIER() asm volatile("s_waitcnt lgkmcnt(0)\ns_barrier" ::: "memory")

// hardware packed f32->bf16 (RNE), 1 instr per pair (no builtin on gfx950)
static __device__ __forceinline__ uint_t cvt_pk_bf16(float lo, float hi) {
    uint_t r;
    asm("v_cvt_pk_bf16_f32 %0, %1, %2" : "=v"(r) : "v"(lo), "v"(hi));
    return r;
}
static __device__ __forceinline__ ushort_t f2bf_hw(float f) {
    return (ushort_t)(cvt_pk_bf16(f, f) & 0xffffu);
}
static __device__ __forceinline__ uint4 pack8(float4 a, float4 b) {
    uint4 r;
    r.x = cvt_pk_bf16(a.x, a.y);
    r.y = cvt_pk_bf16(a.z, a.w);
    r.z = cvt_pk_bf16(b.x, b.y);
    r.w = cvt_pk_bf16(b.z, b.w);
    return r;
}

// ---------------------------------------------------------------------------
// K1: wh = h @ W^T + Wb (bf16) + s_src/s_dst f32 partials (pre-scaled by
// log2e for K2's exp2). wh stored fragment-tiled whB[jt][kh][d][kq][8].
// ---------------------------------------------------------------------------
__launch_bounds__(256, 2)
__global__ void k1_gemm(const float* __restrict__ h, const float* __restrict__ W,
                        const float* __restrict__ Wb, const float* __restrict__ aw,
                        ushort_t* __restrict__ whB, float* __restrict__ s_src,
                        float* __restrict__ s_dst) {
    __shared__ __align__(16) ushort_t aT[256 * 72];  // W tile [o][k], stride 144 B
    __shared__ __align__(16) ushort_t bT[32 * 72];   // h tile [i][k]
    __shared__ float redLds[2][4][32];

    const int t = threadIdx.x;
    const int wv = t >> 6, ln = t & 63;
    const int i0 = blockIdx.x * 32;
    const int srow = t >> 3, sch = t & 7;
    const int row0 = ln & 15, kq = ln >> 4;

    f32x4 acc[4][2];
#pragma unroll
    for (int mt = 0; mt < 4; ++mt)
#pragma unroll
        for (int nt = 0; nt < 2; ++nt) acc[mt][nt] = (f32x4){0.f, 0.f, 0.f, 0.f};

    for (int k0 = 0; k0 < 512; k0 += 64) {
        __syncthreads();
#pragma unroll
        for (int r = 0; r < 8; ++r) {
            const float* gp = W + (size_t)(r * 32 + srow) * 512 + k0 + sch * 8;
            float4 x0 = *(const float4*)gp;
            float4 x1 = *(const float4*)(gp + 4);
            *(uint4*)(aT + (r * 32 + srow) * 72 + sch * 8) = pack8(x0, x1);
        }
        {
            const float* gp = h + (size_t)(i0 + srow) * 512 + k0 + sch * 8;
            float4 x0 = *(const float4*)gp;
            float4 x1 = *(const float4*)(gp + 4);
            *(uint4*)(bT + srow * 72 + sch * 8) = pack8(x0, x1);
        }
        __syncthreads();
#pragma unroll
        for (int ks = 0; ks < 2; ++ks) {
            short8 b[2];
#pragma unroll
            for (int nt = 0; nt < 2; ++nt)
                b[nt] = *(const short8*)(bT + (nt * 16 + row0) * 72 + ks * 32 + kq * 8);
#pragma unroll
            for (int mt = 0; mt < 4; ++mt) {
                short8 a = *(const short8*)(aT + (wv * 64 + mt * 16 + row0) * 72 + ks * 32 + kq * 8);
#pragma unroll
                for (int nt = 0; nt < 2; ++nt)
                    acc[mt][nt] = __builtin_amdgcn_mfma_f32_16x16x32_bf16(a, b[nt], acc[mt][nt], 0, 0, 0);
            }
        }
    }

    float psrc[2] = {0.f, 0.f}, pdst[2] = {0.f, 0.f};
#pragma unroll
    for (int mt = 0; mt < 4; ++mt) {
#pragma unroll
        for (int r = 0; r < 4; ++r) {
            const int o = wv * 64 + mt * 16 + (ln >> 4) * 4 + r;
            const float wbv = Wb[o];
            const float as = aw[o];
            const float ad = aw[256 + o];
#pragma unroll
            for (int nt = 0; nt < 2; ++nt) {
                const float v = acc[mt][nt][r] + wbv;
                psrc[nt] += v * as;
                pdst[nt] += v * ad;
                const int i = i0 + nt * 16 + (ln & 15);
                const int jt = i >> 6;
                const int khi = (i >> 5) & 1;
                const int kqi = (i >> 3) & 3;
                whB[((size_t)(jt * 2 + khi) * 256 + o) * 32 + kqi * 8 + (i & 7)] = f2bf_hw(v);
            }
        }
    }
#pragma unroll
    for (int off = 16; off < 64; off <<= 1) {
#pragma unroll
        for (int nt = 0; nt < 2; ++nt) {
            psrc[nt] += __shfl_xor(psrc[nt], off, 64);
            pdst[nt] += __shfl_xor(pdst[nt], off, 64);
        }
    }
    if (ln < 16) {
#pragma unroll
        for (int nt = 0; nt < 2; ++nt) {
            redLds[0][wv][nt * 16 + ln] = psrc[nt];
            redLds[1][wv][nt * 16 + ln] = pdst[nt];
        }
    }
    __syncthreads();
    if (t < 32) {
        float s = 0.f;
#pragma unroll
        for (int w = 0; w < 4; ++w) s += redLds[0][w][t];
        s_src[i0 + t] = s * LOG2E;  // pre-scaled for K2's exp2
    } else if (t < 64) {
        float s = 0.f;
#pragma unroll
        for (int w = 0; w < 4; ++w) s += redLds[1][w][t - 32];
        s_dst[i0 + t - 32] = s * LOG2E;  // pre-scaled for K2's exp2
    }
}

// ---------------------------------------------------------------------------
// K2: BM=64 i-tiles, grid 128 x jsplit = 256 blocks (1/CU, 8 waves).
// Measured-best r6 structure: depth-1 register prefetch + soft barrier.
// (Depth-2 rotation regressed ~3 us [r8]; 2 blocks/CU regressed ~29 us [r7];
// VALU cuts null [r4]; fence-fused epilogue catastrophic [r5].)
// ---------------------------------------------------------------------------
__launch_bounds__(512, 2)
__global__ void k2_attn(const int* __restrict__ adj, const ushort_t* __restrict__ whB,
                        const float* __restrict__ s_src, const float* __restrict__ s_dst,
                        const float* __restrict__ ab_p, float* __restrict__ out0,
                        float* __restrict__ out1, float* __restrict__ zp, int jsplit) {
    // exch: 256 lanes * 65 f32 stride = 66560 B, unioned with pbuf
    // (2*64*72 ushort = 18432 B, double-buffered p tile). zLds after.
    __shared__ __align__(16) char smem[66560 + 256];
    ushort_t* pbuf = (ushort_t*)smem;
    float* exch = (float*)smem;
    float* zLds = (float*)(smem + 66560);

    const int t = threadIdx.x;
    const int wv = t >> 6, ln = t & 63;
    const int dq = wv & 3, kh = wv >> 2;
    const int row0 = ln & 15, kq = ln >> 4;
    const int split2 = (jsplit == 2);
    const int jb = split2 ? (int)(blockIdx.x & 1) : 0;
    const int ib = split2 ? (int)(blockIdx.x >> 1) : (int)blockIdx.x;
    const int i0 = ib * 64;
    const int jlen = split2 ? 4096 : 8192;
    const int jbase = jb * jlen;
    const int iters = jlen >> 6;
    const int prow = t >> 4, pjc = t & 15;  // p-compute: rows prow & prow+32, 4 j's

    const float ab = ab_p[0] * LOG2E;
    const float ssa0 = s_src[i0 + prow] + ab;        // hoisted ssrc+ab (log2e-scaled)
    const float ssa1 = s_src[i0 + 32 + prow] + ab;

    const int* aBase0 = adj + (size_t)(i0 + prow) * 8192 + jbase + pjc * 4;
    const int* aBase1 = aBase0 + (size_t)32 * 8192;
    const float* sBase = s_dst + jbase + pjc * 4;
    // per-lane B-fragment pointer: contiguous 1 KB per (jt,kh,dq,nt) wave read
    const ushort_t* bBase = whB + ((size_t)(jbase >> 6) * 2 + kh) * 8192
                            + (dq * 64 + row0) * 32 + kq * 8;

    f32x4 acc[4][4];  // [mt][nt]
#pragma unroll
    for (int mt = 0; mt < 4; ++mt)
#pragma unroll
        for (int nt = 0; nt < 4; ++nt) acc[mt][nt] = (f32x4){0.f, 0.f, 0.f, 0.f};
    float zacc0 = 0.f, zacc1 = 0.f;

    // prefetch tile 0 (depth-1)
    i32x4 Av0 = __builtin_nontemporal_load((const i32x4*)aBase0);
    i32x4 Av1 = __builtin_nontemporal_load((const i32x4*)aBase1);
    f32x4 Sv = *(const f32x4*)sBase;
    short8 Bv[4];
#pragma unroll
    for (int nt = 0; nt < 4; ++nt) Bv[nt] = *(const short8*)(bBase + nt * 512);

#pragma unroll 2
    for (int it = 0; it < iters; ++it) {
        const int itn = (it < iters - 1) ? it + 1 : it;
        i32x4 Ac0 = Av0, Ac1 = Av1;
        f32x4 Sc = Sv;
        short8 Bc[4];
#pragma unroll
        for (int nt = 0; nt < 4; ++nt) Bc[nt] = Bv[nt];
        // issue next-tile loads (stay in flight across the soft barrier)
        Av0 = __builtin_nontemporal_load((const i32x4*)(aBase0 + itn * 64));
        Av1 = __builtin_nontemporal_load((const i32x4*)(aBase1 + itn * 64));
        Sv = *(const f32x4*)(sBase + itn * 64);
        {
            const ushort_t* bN = bBase + (size_t)itn * 16384;
#pragma unroll
            for (int nt = 0; nt < 4; ++nt) Bv[nt] = *(const short8*)(bN + nt * 512);
        }

        // p tile (both rows) for this iteration -> pbuf[it&1]
        {
            ushort_t* pc = pbuf + (it & 1) * 4608;
            float p[4];
            float z4 = 0.f;
#pragma unroll
            for (int k = 0; k < 4; ++k) {
                float sc = ssa0 + Sc[k];
                sc = fmaxf(sc, LRELU_SLOPE * sc);   // lrelu (log2e-scaled domain)
                sc = fminf(sc, 86.562f);            // 60 * log2e
                float pv = (Ac0[k] > 0) ? __builtin_amdgcn_exp2f(sc) : 0.f;
                z4 += pv;
                p[k] = pv;
            }
            zacc0 += z4;
            uint2 w0;
            w0.x = cvt_pk_bf16(p[0], p[1]);
            w0.y = cvt_pk_bf16(p[2], p[3]);
            *(uint2*)(pc + prow * 72 + pjc * 4) = w0;
            z4 = 0.f;
#pragma unroll
            for (int k = 0; k < 4; ++k) {
                float sc = ssa1 + Sc[k];
                sc = fmaxf(sc, LRELU_SLOPE * sc);
                sc = fminf(sc, 86.562f);
                float pv = (Ac1[k] > 0) ? __builtin_amdgcn_exp2f(sc) : 0.f;
                z4 += pv;
                p[k] = pv;
            }
            zacc1 += z4;
            uint2 w1;
            w1.x = cvt_pk_bf16(p[0], p[1]);
            w1.y = cvt_pk_bf16(p[2], p[3]);
            *(uint2*)(pc + (32 + prow) * 72 + pjc * 4) = w1;
        }
        SOFT_BARRIER();  // p visible (lgkm drained); global prefetches stay in flight
        {
            const ushort_t* pc = pbuf + (it & 1) * 4608;
#pragma unroll
            for (int mt = 0; mt < 4; ++mt) {
                short8 a = *(const short8*)(pc + (mt * 16 + row0) * 72 + kh * 32 + kq * 8);
#pragma unroll
                for (int nt = 0; nt < 4; ++nt)
                    acc[mt][nt] = __builtin_amdgcn_mfma_f32_16x16x32_bf16(a, Bc[nt], acc[mt][nt], 0, 0, 0);
            }
        }
    }

    // per-row Z from the 16 consecutive lanes of each prow group
    zacc0 += __shfl_xor(zacc0, 1, 64);
    zacc1 += __shfl_xor(zacc1, 1, 64);
    zacc0 += __shfl_xor(zacc0, 2, 64);
    zacc1 += __shfl_xor(zacc1, 2, 64);
    zacc0 += __shfl_xor(zacc0, 4, 64);
    zacc1 += __shfl_xor(zacc1, 4, 64);
    zacc0 += __shfl_xor(zacc0, 8, 64);
    zacc1 += __shfl_xor(zacc1, 8, 64);
    if ((t & 15) == 0) {
        if (split2) {
            zp[(size_t)jb * 8192 + i0 + prow] = zacc0;
            zp[(size_t)jb * 8192 + i0 + 32 + prow] = zacc1;
        } else {
            zLds[prow] = 1.0f / fmaxf(zacc0, 1e-30f);
            zLds[32 + prow] = 1.0f / fmaxf(zacc1, 1e-30f);
        }
    }

    __syncthreads();  // full barrier: all MFMA LDS reads done; pbuf -> exch reuse
    if (kh == 1) {
        float* p = exch + (dq * 64 + ln) * 65;  // stride-65: conflict-free
#pragma unroll
        for (int mt = 0; mt < 4; ++mt)
#pragma unroll
            for (int nt = 0; nt < 4; ++nt)
#pragma unroll
                for (int r = 0; r < 4; ++r) p[mt * 16 + nt * 4 + r] = acc[mt][nt][r];
    }
    __syncthreads();
    if (kh == 0) {
        float* outp = (jb == 0) ? out0 : out1;
        const float* p = exch + (dq * 64 + ln) * 65;
#pragma unroll
        for (int mt = 0; mt < 4; ++mt)
#pragma unroll
            for (int nt = 0; nt < 4; ++nt)
#pragma unroll
                for (int r = 0; r < 4; ++r) {
                    const int il = mt * 16 + (ln >> 4) * 4 + r;
                    const int d = dq * 64 + nt * 16 + (ln & 15);
                    const float v = acc[mt][nt][r] + p[mt * 16 + nt * 4 + r];
                    if (split2)
                        outp[(size_t)(i0 + il) * 256 + d] = v;
                    else
                        outp[(size_t)(i0 + il) * 256 + d] = v * zLds[il];
                }
    }
}

// ---------------------------------------------------------------------------
// K3 (jsplit==2 only): out = (out + part) / (z0 + z1). grid 8192 x 256.
// ---------------------------------------------------------------------------
__global__ void k3_norm(float* __restrict__ out, const float* __restrict__ part,
                        const float* __restrict__ zp) {
    const int i = blockIdx.x, t = threadIdx.x;
    const float rz = 1.0f / fmaxf(zp[i] + zp[8192 + i], 1e-30f);
    const size_t idx = (size_t)i * 256 + t;
    out[idx] = (out[idx] + part[idx]) * rz;
}

extern "C" void kernel_launch(void* const* d_in, const int* in_sizes, int n_in, void* d_out,
                              int out_size, void* d_ws, size_t ws_size, hipStream_t stream) {
    // identify inputs by flat size (validated r7/r8)
    int order[16];
    for (int i = 0; i < n_in; ++i) order[i] = i;
    for (int a = 0; a < n_in; ++a)
        for (int b = a + 1; b < n_in; ++b)
            if (in_sizes[order[b]] < in_sizes[order[a]]) {
                int tmp = order[a]; order[a] = order[b]; order[b] = tmp;
            }
    const float* ab = (const float*)d_in[order[0]];
    const float* Wb = (const float*)d_in[order[1]];
    const float* aw = (const float*)d_in[order[2]];
    const float* Ww = (const float*)d_in[order[3]];
    const float* h = (const float*)d_in[order[4]];
    const int* adj = (const int*)d_in[order[5]];

    char* ws = (char*)d_ws;
    ushort_t* whB = (ushort_t*)ws;                 // 4 MB (fragment-tiled wh)
    float* ssrc = (float*)(ws + 4194304);          // 32 KB
    float* sdst = (float*)(ws + 4227072);          // 32 KB
    float* part = (float*)(ws + 4259840);          // 8 MB (jb=1 partial)
    float* zp = (float*)(ws + 12648448);           // 64 KB (2 x 8192 f32)
    const size_t need = 12713984;
    const int jsplit = (ws_size >= need) ? 2 : 1;

    hipLaunchKernelGGL(k1_gemm, dim3(256), dim3(256), 0, stream, h, Ww, Wb, aw, whB, ssrc, sdst);
    hipLaunchKernelGGL(k2_attn, dim3(128 * jsplit), dim3(512), 0, stream, adj, whB, ssrc, sdst,
                       ab, (float*)d_out, part, zp, jsplit);
    if (jsplit == 2)
        hipLaunchKernelGGL(k3_norm, dim3(8192), dim3(256), 0, stream, (float*)d_out, part, zp);
}